// Round 6
// baseline (7657.873 us; speedup 1.0000x reference)
//
#include <hip/hip_runtime.h>

#define TT 1024
#define RD 8                // ring depth (slots)
#define SLOT 65536          // f16 elements per ring slot (256 rows x 256 units)
#define POIS 0x7F7F7F7Fu    // 0x7F7F fp16 = NaN; h = sig*tanh can never be NaN

typedef _Float16 f16;
typedef _Float16 f16x8 __attribute__((ext_vector_type(8)));
typedef float f32x4 __attribute__((ext_vector_type(4)));
typedef unsigned long long u64;

__device__ __forceinline__ float sigmoidf_(float x) { return 1.0f / (1.0f + __expf(-x)); }
__device__ __forceinline__ float tanhf_(float x) { return 1.0f - 2.0f / (__expf(2.0f * x) + 1.0f); }

__device__ __forceinline__ u64 aload(const u64* p) {
  return __hip_atomic_load(p, __ATOMIC_RELAXED, __HIP_MEMORY_SCOPE_AGENT);
}

// Speculative tagged consumption: spin-load N 16B chunks (stride 32 f16) until no
// 32-bit word equals POISON. 4B stores are atomic, so any torn/partial state still
// shows poison in the unwritten words. The detecting load IS the data load —
// no flag, no producer drain, no separate fetch.
template <int N>
__device__ __forceinline__ void spin_chunks(const f16* base, f16x8* a) {
  for (;;) {
    u64 v[2 * N];
#pragma unroll
    for (int c = 0; c < N; ++c) {
      v[2 * c]     = aload((const u64*)(base + c * 32));
      v[2 * c + 1] = aload((const u64*)(base + c * 32) + 1);
    }
    bool ok = true;
#pragma unroll
    for (int k = 0; k < 2 * N; ++k)
      ok = ok && ((unsigned)v[k] != POIS) && ((unsigned)(v[k] >> 32) != POIS);
    if (__all(ok)) {
#pragma unroll
      for (int c = 0; c < N; ++c) {
        union { u64 q[2]; f16x8 f; } u;
        u.q[0] = v[2 * c]; u.q[1] = v[2 * c + 1];
        a[c] = u.f;
      }
      return;
    }
    __builtin_amdgcn_s_sleep(1);
  }
}

// Dataflow LSTM, no barriers. Each WG: 8 hidden units x 64 batch rows; weights in
// registers for all 1024 steps. h rings depth 8; slot s holds h[t] for t%8==s;
// slot 7 pre-zeroed = h[-1]. Producer at step t re-poisons slot (t+4)&7 (holding
// step t-4 data; all consumers provably done; >=4-step visibility slack orders the
// poison before any future poll). L0 additionally back-pressures on L1's done
// epoch (>= t-3) before re-poisoning h1 slots — off the critical path.
template <int LAYER>
__device__ void run_layer(const float* __restrict__ xin,
                          const float* __restrict__ Wih, const float* __restrict__ Whh,
                          const float* __restrict__ bias,
                          f16* __restrict__ hself, f16* __restrict__ hin,
                          unsigned* doneblk, float (*Gs)[33], int bid, int tid) {
  constexpr int NCH = (LAYER == 0) ? 12 : 16;
  constexpr int DIN = (LAYER == 0) ? 128 : 256;

  const int lane = tid & 63, wave = tid >> 6;
  const int q = lane >> 4, mm = lane & 15;
  const int lb = bid & 127;
  const int ng = lb >> 2, ms = lb & 3;
  const int b0r = ms * 64, u0 = ng * 8;

  // epilogue mapping: each thread owns 1 batch row x 2 adjacent units (4B store)
  const int up_e = tid & 3, bl_e = tid >> 2;
  const int uc0 = u0 + 2 * up_e, uc1 = uc0 + 1;
  const float bi0 = bias[uc0],       bi1 = bias[uc1];
  const float bf0 = bias[256 + uc0], bf1 = bias[256 + uc1];
  const float bg0 = bias[512 + uc0], bg1 = bias[512 + uc1];
  const float bo0 = bias[768 + uc0], bo1 = bias[768 + uc1];

  // B-fragment preload: B[k=(lane>>4)*8+j][n=lane&15], W row = gate*256+u0+unit
  const int row0 = ((mm >> 3)) * 256 + u0 + (mm & 7);      // gates i,f
  const int row1 = ((mm >> 3) + 2) * 256 + u0 + (mm & 7);  // gates g,o
  f16x8 bA[NCH], bB[NCH];
#pragma unroll
  for (int c = 0; c < NCH; ++c) {
    const int k0 = c * 32 + q * 8;
    const float* s0 = (c < 8) ? (Whh + row0 * 256 + k0) : (Wih + row0 * DIN + (k0 - 256));
    const float* s1 = (c < 8) ? (Whh + row1 * 256 + k0) : (Wih + row1 * DIN + (k0 - 256));
    f16x8 v0, v1;
#pragma unroll
    for (int j = 0; j < 8; ++j) { v0[j] = (f16)s0[j]; v1[j] = (f16)s1[j]; }
    bA[c] = v0; bB[c] = v1;
  }

  float cA = 0.f, cB = 0.f;
  const int brow = b0r + wave * 16 + mm;
  const int fragoff = brow * 256 + q * 8;

  float4 axr[8];  // raw fp32 x for next step
  f16x8 ax[4];
  if (LAYER == 0) {
    const float* px = xin + (brow * 1024 + 0) * 128 + q * 8;
#pragma unroll
    for (int c = 0; c < 4; ++c) {
      axr[2 * c]     = *(const float4*)(px + c * 32);
      axr[2 * c + 1] = *(const float4*)(px + c * 32 + 4);
    }
  }

  for (int t = 0; t < TT; ++t) {
    if (LAYER == 0) {
      // x[t] fp32->fp16 (loaded last iter; slack >= 1 step); issue x[t+1] loads
#pragma unroll
      for (int c = 0; c < 4; ++c) {
        const float4 fa = axr[2 * c], fb = axr[2 * c + 1];
        f16x8 v; v[0]=(f16)fa.x; v[1]=(f16)fa.y; v[2]=(f16)fa.z; v[3]=(f16)fa.w;
        v[4]=(f16)fb.x; v[5]=(f16)fb.y; v[6]=(f16)fb.z; v[7]=(f16)fb.w;
        ax[c] = v;
      }
      if (t + 1 < TT) {
        const float* px = xin + (brow * 1024 + (t + 1)) * 128 + q * 8;
#pragma unroll
        for (int c = 0; c < 4; ++c) {
          axr[2 * c]     = *(const float4*)(px + c * 32);
          axr[2 * c + 1] = *(const float4*)(px + c * 32 + 4);
        }
      }
      // back-pressure: h1 slot (t+4)&7 holds h1[t-4], consumed by L1 at its step
      // t-4 -> require L1 done epoch >= t-3 before destroying it
      if (t >= 4) {
        const unsigned need = (unsigned)(t - 3);
        for (;;) {
          unsigned v = need;
          if (lane < 32) v = __hip_atomic_load(doneblk + lane * 64, __ATOMIC_RELAXED,
                                               __HIP_MEMORY_SCOPE_AGENT);
          if (__all(v >= need)) break;
          __builtin_amdgcn_s_sleep(2);
        }
      }
    }

    // re-poison own region of slot (t+4)&7 (holds step t-4 data; consumers done)
    {
      unsigned* pp = (unsigned*)(hself + ((t + 4) & 7) * SLOT + (b0r + bl_e) * 256 + uc0);
      __hip_atomic_store(pp, POIS, __ATOMIC_RELAXED, __HIP_MEMORY_SCOPE_AGENT);
    }

    // inputs: spin-consume h[t-1] (slot (t+7)&7; t=0 -> pre-zeroed slot 7)
    f16x8 a[NCH];
    spin_chunks<8>(hself + ((t + 7) & 7) * SLOT + fragoff, a);
    if (LAYER == 0) {
#pragma unroll
      for (int c = 8; c < 12; ++c) a[c] = ax[c - 8];
    } else {
      // h1[t] straight from layer 0, same step index
      spin_chunks<8>(hin + (t & 7) * SLOT + fragoff, a + 8);
    }

    f32x4 acc0 = {0.f, 0.f, 0.f, 0.f}, acc1 = {0.f, 0.f, 0.f, 0.f};
#pragma unroll
    for (int c = 0; c < NCH; ++c) {
      acc0 = __builtin_amdgcn_mfma_f32_16x16x32_f16(a[c], bA[c], acc0, 0, 0, 0);
      acc1 = __builtin_amdgcn_mfma_f32_16x16x32_f16(a[c], bB[c], acc1, 0, 0, 0);
    }
    // C/D layout: col=lane&15 (gate unit), row=(lane>>4)*4+reg (batch)
#pragma unroll
    for (int r = 0; r < 4; ++r) {
      Gs[wave * 16 + q * 4 + r][mm] = acc0[r];
      Gs[wave * 16 + q * 4 + r][16 + mm] = acc1[r];
    }
    __syncthreads();
    {
      const float gi0 = Gs[bl_e][2 * up_e] + bi0,      gi1 = Gs[bl_e][2 * up_e + 1] + bi1;
      const float gf0 = Gs[bl_e][8 + 2 * up_e] + bf0,  gf1 = Gs[bl_e][8 + 2 * up_e + 1] + bf1;
      const float gg0 = Gs[bl_e][16 + 2 * up_e] + bg0, gg1 = Gs[bl_e][16 + 2 * up_e + 1] + bg1;
      const float go0 = Gs[bl_e][24 + 2 * up_e] + bo0, go1 = Gs[bl_e][24 + 2 * up_e + 1] + bo1;
      cA = sigmoidf_(gf0) * cA + sigmoidf_(gi0) * tanhf_(gg0);
      cB = sigmoidf_(gf1) * cB + sigmoidf_(gi1) * tanhf_(gg1);
      union { f16 h2v[2]; unsigned u; } pk;
      pk.h2v[0] = (f16)(sigmoidf_(go0) * tanhf_(cA));
      pk.h2v[1] = (f16)(sigmoidf_(go1) * tanhf_(cB));
      unsigned* dst = (unsigned*)(hself + (t & 7) * SLOT + (b0r + bl_e) * 256 + uc0);
      __hip_atomic_store(dst, pk.u, __ATOMIC_RELAXED, __HIP_MEMORY_SCOPE_AGENT);
    }

    if (LAYER == 1 && tid == 0) {
      // done epoch: h1[t] fully consumed (loads completed before MFMA issued)
      __atomic_signal_fence(__ATOMIC_SEQ_CST);
      __hip_atomic_store(doneblk + ng * 64, (unsigned)(t + 1), __ATOMIC_RELAXED,
                         __HIP_MEMORY_SCOPE_AGENT);
    }
    __syncthreads();  // protect Gs reuse next iteration
  }
}

__global__ __launch_bounds__(256, 1) void lstm_persistent(
    const float* __restrict__ x,
    const float* __restrict__ Wih0, const float* __restrict__ Whh0, const float* __restrict__ b0v,
    const float* __restrict__ Wih1, const float* __restrict__ Whh1, const float* __restrict__ b1v,
    f16* h1ring, f16* h2ring, unsigned* F) {
  __shared__ float Gs[64][33];
  const int tid = threadIdx.x, bid = blockIdx.x;
  const int ms = (bid & 127) & 3;
  unsigned* doneblk = F + ms * 2048;  // 32 slots x 64 u32 (256B apart) per block

  if (bid < 128)
    run_layer<0>(x, Wih0, Whh0, b0v, h1ring, nullptr, doneblk, Gs, bid, tid);
  else
    run_layer<1>(nullptr, Wih1, Whh1, b1v, h2ring, h1ring, doneblk, Gs, bid, tid);
}

// final dense (C=10) + softmax on h2[T-1]; one wave per batch row
__global__ __launch_bounds__(64, 1) void dense_softmax_k(const f16* __restrict__ h2,
                                                         const float* __restrict__ Wd,
                                                         const float* __restrict__ bd,
                                                         float* __restrict__ out) {
  const int b = blockIdx.x, lane = threadIdx.x;
  float hv[4];
#pragma unroll
  for (int j = 0; j < 4; ++j) hv[j] = (float)h2[b * 256 + lane + 64 * j];
  float p[10];
#pragma unroll
  for (int c = 0; c < 10; ++c) {
    float s = 0.f;
#pragma unroll
    for (int j = 0; j < 4; ++j) s += hv[j] * Wd[c * 256 + lane + 64 * j];
#pragma unroll
    for (int off = 32; off >= 1; off >>= 1) s += __shfl_xor(s, off, 64);
    p[c] = s;
  }
  if (lane == 0) {
    float mx = -1e30f;
#pragma unroll
    for (int c = 0; c < 10; ++c) { p[c] += bd[c]; mx = fmaxf(mx, p[c]); }
    float den = 0.f;
#pragma unroll
    for (int c = 0; c < 10; ++c) { p[c] = __expf(p[c] - mx); den += p[c]; }
#pragma unroll
    for (int c = 0; c < 10; ++c) out[b * 10 + c] = p[c] / den;
  }
}

extern "C" void kernel_launch(void* const* d_in, const int* in_sizes, int n_in,
                              void* d_out, int out_size, void* d_ws, size_t ws_size,
                              hipStream_t stream) {
  const float* x    = (const float*)d_in[0];
  const float* Wih0 = (const float*)d_in[1];
  const float* Whh0 = (const float*)d_in[2];
  const float* b0v  = (const float*)d_in[3];
  const float* Wih1 = (const float*)d_in[4];
  const float* Whh1 = (const float*)d_in[5];
  const float* b1v  = (const float*)d_in[6];
  const float* Wd   = (const float*)d_in[7];
  const float* bd   = (const float*)d_in[8];

  char* ws = (char*)d_ws;
  // layout: h1ring @0 (1MB, 8 slots x 128KB) | h2ring @1MB (1MB) | done flags @2MB (32KB)
  f16* h1ring = (f16*)(ws);
  f16* h2ring = (f16*)(ws + (1 << 20));
  unsigned* F = (unsigned*)(ws + (2 << 20));

  // poison both rings, then zero slot 7 of each (h[-1] initial state), zero done flags
  hipMemsetAsync(ws, 0x7F, 2 << 20, stream);
  hipMemsetAsync(ws + 7 * 131072, 0, 131072, stream);
  hipMemsetAsync(ws + (1 << 20) + 7 * 131072, 0, 131072, stream);
  hipMemsetAsync(ws + (2 << 20), 0, 32768, stream);

  lstm_persistent<<<256, 256, 0, stream>>>(x, Wih0, Whh0, b0v, Wih1, Whh1, b1v,
                                           h1ring, h2ring, F);
  // h2[T-1] = h2[1023] lands in ring slot 1023 & 7 = 7
  dense_softmax_k<<<256, 64, 0, stream>>>(h2ring + 7 * SLOT, Wd, bd, (float*)d_out);
}